// Round 1
// baseline (152.624 us; speedup 1.0000x reference)
//
#include <hip/hip_runtime.h>

// Biharmonic Jacobi relaxation, 32 sweeps, fused into ONE kernel via temporal
// blocking in registers.
//
// Layout: N=1048576 rows x B=8 cols fp32, stencil radius 2 along rows.
// Each block: 1024 output rows + 64-row halo each side = 1152-row region.
// 256 threads = 32 segments x 8 cols; each thread holds 36 rows (buf + y) in
// VGPRs. Per sweep only the 2-row segment halo is exchanged through a small
// double-buffered LDS array (one __syncthreads per sweep).
//
// Correctness of halo: region-edge rows are frozen (copy-old). Wrongness from
// frozen edges propagates exactly 2 rows/sweep -> 64 rows after 32 sweeps,
// which is precisely the discarded halo. Global boundary rules (row 0 copy,
// row 1 one-sided, rows N-2/N-1 stay =y) are exact, so edge blocks need no
// out-of-domain halo.

namespace {
constexpr int kN = 1048576;
constexpr int kSweeps = 32;              // NUM_ITERATION + 1
constexpr int kTile = 1024;              // output rows per block
constexpr int kHalo = 64;                // 2 rows/sweep * 32 sweeps
constexpr int kTot = kTile + 2 * kHalo;  // 1152 region rows
constexpr int kGroups = 32;              // 256 threads / 8 columns
constexpr int kS = kTot / kGroups;       // 36 rows per thread
constexpr float kC1 = 0.005f;            // ni * (1 - beta)
constexpr float kC2 = 0.005f;            // ni * beta
}  // namespace

template <bool EDGE>
__device__ __forceinline__ void run_body(const float* __restrict__ y,
                                         float* __restrict__ out,
                                         float4 (*halo)[kGroups][8]) {
  const int tid = (int)threadIdx.x;
  const int b = tid & 7;    // column
  const int g = tid >> 3;   // row segment
  const int base = (int)blockIdx.x * kTile;
  const int seg = base - kHalo + g * kS;  // global row of buf[0] (may be <0)

  float buf[kS];
  float yv[kS];
#pragma unroll
  for (int r = 0; r < kS; ++r) {
    const int gi = seg + r;
    float v;
    if (EDGE) {
      v = (gi >= 0 && gi < kN) ? y[gi * 8 + b] : 0.0f;
    } else {
      v = y[gi * 8 + b];
    }
    yv[r] = v;
    buf[r] = v;
  }

  for (int s = 0; s < kSweeps; ++s) {
    const int p = s & 1;
    // Publish this sweep's OLD segment-boundary values.
    const float4 h = make_float4(buf[0], buf[1], buf[kS - 2], buf[kS - 1]);
    halo[p][g][b] = h;
    __syncthreads();
    float om2 = 0.0f, om1 = 0.0f, hp1 = 0.0f, hp2 = 0.0f;
    if (g > 0) {
      const float4 t = halo[p][g - 1][b];
      om2 = t.z;  // old row seg-2
      om1 = t.w;  // old row seg-1
    }
    if (g < kGroups - 1) {
      const float4 t = halo[p][g + 1][b];
      hp1 = t.x;  // old row seg+kS
      hp2 = t.y;  // old row seg+kS+1
    }

    auto upd = [&](int r, float a2, float a1, float c, float d1,
                   float d2) -> float {
      if (EDGE) {
        const int gi = seg + r;
        const int lr = g * kS + r;
        float lap = a2 - 4.0f * a1 + 6.0f * c - 4.0f * d1 + d2;
        if (gi == 1) lap = -2.0f * a1 + 5.0f * c - 4.0f * d1 + d2;
        const float nv = c - kC1 * lap - kC2 * (c - yv[r]);
        const bool frozen =
            (gi <= 0) || (gi >= kN - 2) || (lr < 2) || (lr >= kTot - 2);
        return frozen ? c : nv;
      } else {
        // 7 VALU ops, branch-free.
        float lap = fmaf(-4.0f, a1, a2);
        lap = fmaf(6.0f, c, lap);
        lap = fmaf(-4.0f, d1, lap);
        lap += d2;
        const float t = fmaf(-kC2, c - yv[r], c);
        return fmaf(-kC1, lap, t);
      }
    };

    // In-place Jacobi with a 2-deep old-value window (om2, om1).
#pragma unroll
    for (int r = 0; r < kS - 2; ++r) {
      const float o0 = buf[r];
      const float nv = upd(r, om2, om1, o0, buf[r + 1], buf[r + 2]);
      buf[r] = nv;
      om2 = om1;
      om1 = o0;
    }
    {  // r = kS-2 (reads one halo value)
      const float o0 = buf[kS - 2];
      const float nv = upd(kS - 2, om2, om1, o0, buf[kS - 1], hp1);
      buf[kS - 2] = nv;
      om2 = om1;
      om1 = o0;
    }
    {  // r = kS-1 (reads two halo values)
      const float o0 = buf[kS - 1];
      const float nv = upd(kS - 1, om2, om1, o0, hp1, hp2);
      buf[kS - 1] = nv;
    }
    if (!EDGE) {
      // Freeze the 2 region-edge rows on each side: restore old values
      // (captured in h at sweep start). Only g==0 / g==31 touched.
      if (g == 0) {
        buf[0] = h.x;
        buf[1] = h.y;
      }
      if (g == kGroups - 1) {
        buf[kS - 2] = h.z;
        buf[kS - 1] = h.w;
      }
    }
  }

  // Store only the valid 1024-row window.
#pragma unroll
  for (int r = 0; r < kS; ++r) {
    const int lr = g * kS + r;
    if (lr >= kHalo && lr < kHalo + kTile) {
      out[(seg + r) * 8 + b] = buf[r];
    }
  }
}

__global__ __launch_bounds__(256, 4) void biharm_kernel(
    const float* __restrict__ y, float* __restrict__ out) {
  __shared__ float4 halo[2][kGroups][8];  // 8 KB, double-buffered per sweep
  // Branch is block-uniform -> __syncthreads inside is safe.
  if (blockIdx.x == 0 || blockIdx.x == (int)gridDim.x - 1) {
    run_body<true>(y, out, halo);
  } else {
    run_body<false>(y, out, halo);
  }
}

extern "C" void kernel_launch(void* const* d_in, const int* in_sizes, int n_in,
                              void* d_out, int out_size, void* d_ws,
                              size_t ws_size, hipStream_t stream) {
  const float* yp = (const float*)d_in[0];
  float* outp = (float*)d_out;
  biharm_kernel<<<dim3(kN / kTile), dim3(256), 0, stream>>>(yp, outp);
}

// Round 2
// 138.236 us; speedup vs baseline: 1.1041x; 1.1041x over previous
//
#include <hip/hip_runtime.h>

// Biharmonic Jacobi relaxation, 32 sweeps, fused into ONE kernel via temporal
// blocking in registers.
//
// R2 changes vs R1:
//  - 512 threads/block (64 segments x 8 cols), 18 rows/thread -> 36 state
//    floats + temps fits the allocator's 64-VGPR / 8-wave-per-SIMD target
//    WITHOUT spilling (R1 had 72 floats @ 64 VGPRs -> ~70MB scratch writes).
//  - Halo exchanged via 4 scalar LDS planes indexed by tid (bank = tid%32,
//    2 lanes/bank = conflict-free) instead of float4 [g][b] (was 8-way).
//  - Row update reduced 7 -> 5 VALU ops: precompute ky = kC2*y, fold
//    constants: new = cc*c + 4kC1*(a1+d1) - kC1*(a2+d2) + ky.

namespace {
constexpr int kN = 1048576;
constexpr int kSweeps = 32;              // NUM_ITERATION + 1
constexpr int kTile = 1024;              // output rows per block
constexpr int kHalo = 64;                // 2 rows/sweep * 32 sweeps
constexpr int kTot = kTile + 2 * kHalo;  // 1152 region rows
constexpr int kThreads = 512;
constexpr int kGroups = kThreads / 8;    // 64 row segments
constexpr int kS = kTot / kGroups;       // 18 rows per thread
constexpr float kC1 = 0.005f;            // ni * (1 - beta)
constexpr float kC2 = 0.005f;            // ni * beta
constexpr float kCC = 1.0f - 6.0f * kC1 - kC2;  // 0.965
constexpr float k4C1 = 4.0f * kC1;              // 0.02
}  // namespace

template <bool EDGE>
__device__ __forceinline__ void run_body(const float* __restrict__ y,
                                         float* __restrict__ out,
                                         float (*h0)[kThreads],
                                         float (*h1)[kThreads],
                                         float (*h2)[kThreads],
                                         float (*h3)[kThreads]) {
  const int tid = (int)threadIdx.x;
  const int b = tid & 7;    // column
  const int g = tid >> 3;   // row segment
  const int base = (int)blockIdx.x * kTile;
  const int seg = base - kHalo + g * kS;  // global row of buf[0] (may be <0)

  float buf[kS];
  float ky[kS];  // kC2 * y (pre-scaled)
#pragma unroll
  for (int r = 0; r < kS; ++r) {
    const int gi = seg + r;
    float v;
    if (EDGE) {
      v = (gi >= 0 && gi < kN) ? y[gi * 8 + b] : 0.0f;
    } else {
      v = y[gi * 8 + b];
    }
    buf[r] = v;
    ky[r] = kC2 * v;
  }

  for (int s = 0; s < kSweeps; ++s) {
    const int p = s & 1;
    // Publish this sweep's OLD segment-boundary values. tid-indexed scalar
    // planes: bank = tid % 32 -> 2 lanes/bank, conflict-free.
    const float h0v = buf[0], h1v = buf[1];
    const float h2v = buf[kS - 2], h3v = buf[kS - 1];
    h0[p][tid] = h0v;
    h1[p][tid] = h1v;
    h2[p][tid] = h2v;
    h3[p][tid] = h3v;
    __syncthreads();
    float om2 = 0.0f, om1 = 0.0f, hp1 = 0.0f, hp2 = 0.0f;
    if (g > 0) {
      om2 = h2[p][tid - 8];  // old row seg-2
      om1 = h3[p][tid - 8];  // old row seg-1
    }
    if (g < kGroups - 1) {
      hp1 = h0[p][tid + 8];  // old row seg+kS
      hp2 = h1[p][tid + 8];  // old row seg+kS+1
    }

    auto upd = [&](int r, float a2, float a1, float c, float d1,
                   float d2) -> float {
      if (EDGE) {
        const int gi = seg + r;
        const int lr = g * kS + r;
        float lap = a2 - 4.0f * a1 + 6.0f * c - 4.0f * d1 + d2;
        if (gi == 1) lap = -2.0f * a1 + 5.0f * c - 4.0f * d1 + d2;
        const float t = fmaf(-kC2, c, c) + ky[r];
        const float nv = fmaf(-kC1, lap, t);
        const bool frozen =
            (gi <= 0) || (gi >= kN - 2) || (lr < 2) || (lr >= kTot - 2);
        return frozen ? c : nv;
      } else {
        // 5 VALU ops, branch-free.
        float nv = fmaf(kCC, c, ky[r]);
        nv = fmaf(k4C1, a1 + d1, nv);
        nv = fmaf(-kC1, a2 + d2, nv);
        return nv;
      }
    };

    // In-place Jacobi with a 2-deep old-value window (om2, om1).
#pragma unroll
    for (int r = 0; r < kS - 2; ++r) {
      const float o0 = buf[r];
      const float nv = upd(r, om2, om1, o0, buf[r + 1], buf[r + 2]);
      buf[r] = nv;
      om2 = om1;
      om1 = o0;
    }
    {  // r = kS-2 (reads one halo value)
      const float o0 = buf[kS - 2];
      const float nv = upd(kS - 2, om2, om1, o0, buf[kS - 1], hp1);
      buf[kS - 2] = nv;
      om2 = om1;
      om1 = o0;
    }
    {  // r = kS-1 (reads two halo values)
      const float o0 = buf[kS - 1];
      const float nv = upd(kS - 1, om2, om1, o0, hp1, hp2);
      buf[kS - 1] = nv;
    }
    if (!EDGE) {
      // Freeze the 2 region-edge rows on each side (restore sweep-start old
      // values). Garbage from here propagates 2 rows/sweep -> 64 rows = the
      // discarded halo.
      if (g == 0) {
        buf[0] = h0v;
        buf[1] = h1v;
      }
      if (g == kGroups - 1) {
        buf[kS - 2] = h2v;
        buf[kS - 1] = h3v;
      }
    }
  }

  // Store only the valid 1024-row window.
#pragma unroll
  for (int r = 0; r < kS; ++r) {
    const int lr = g * kS + r;
    if (lr >= kHalo && lr < kHalo + kTile) {
      out[(seg + r) * 8 + b] = buf[r];
    }
  }
}

__global__ __launch_bounds__(kThreads, 8) void biharm_kernel(
    const float* __restrict__ y, float* __restrict__ out) {
  __shared__ float h0[2][kThreads];  // 4 scalar planes, double-buffered
  __shared__ float h1[2][kThreads];  // total 16 KB
  __shared__ float h2[2][kThreads];
  __shared__ float h3[2][kThreads];
  // Branch is block-uniform -> __syncthreads inside is safe.
  if (blockIdx.x == 0 || blockIdx.x == (int)gridDim.x - 1) {
    run_body<true>(y, out, h0, h1, h2, h3);
  } else {
    run_body<false>(y, out, h0, h1, h2, h3);
  }
}

extern "C" void kernel_launch(void* const* d_in, const int* in_sizes, int n_in,
                              void* d_out, int out_size, void* d_ws,
                              size_t ws_size, hipStream_t stream) {
  const float* yp = (const float*)d_in[0];
  float* outp = (float*)d_out;
  biharm_kernel<<<dim3(kN / kTile), dim3(kThreads), 0, stream>>>(yp, outp);
}

// Round 3
// 131.320 us; speedup vs baseline: 1.1622x; 1.0527x over previous
//
#include <hip/hip_runtime.h>

// Biharmonic Jacobi relaxation, 32 sweeps, fused into ONE kernel via temporal
// blocking in registers.
//
// R3 changes vs R2:
//  - __launch_bounds__(512, 6): R2's (512,8) capped regs at 64 -> compiler
//    put ~half the 36-float state in AGPRs (CSV showed VGPR_Count=32), adding
//    v_accvgpr_read/write on every state access (~+50% VALU ops, VALUBusy
//    stuck at 53%). 85-reg budget fits all state in arch VGPRs; if usage
//    lands <=64 we still get 8 waves/SIMD.
//  - Halo packed as float2 LDS planes (ds_*_b64): 4 DS instrs per wave-sweep
//    instead of 8, keeping the per-CU LDS pipe off the critical path.

namespace {
constexpr int kN = 1048576;
constexpr int kSweeps = 32;              // NUM_ITERATION + 1
constexpr int kTile = 1024;              // output rows per block
constexpr int kHalo = 64;                // 2 rows/sweep * 32 sweeps
constexpr int kTot = kTile + 2 * kHalo;  // 1152 region rows
constexpr int kThreads = 512;
constexpr int kGroups = kThreads / 8;    // 64 row segments
constexpr int kS = kTot / kGroups;       // 18 rows per thread
constexpr float kC1 = 0.005f;            // ni * (1 - beta)
constexpr float kC2 = 0.005f;            // ni * beta
constexpr float kCC = 1.0f - 6.0f * kC1 - kC2;  // 0.965
constexpr float k4C1 = 4.0f * kC1;              // 0.02
}  // namespace

template <bool EDGE>
__device__ __forceinline__ void run_body(const float* __restrict__ y,
                                         float* __restrict__ out,
                                         float2 (*hA)[kThreads],
                                         float2 (*hB)[kThreads]) {
  const int tid = (int)threadIdx.x;
  const int b = tid & 7;    // column
  const int g = tid >> 3;   // row segment
  const int base = (int)blockIdx.x * kTile;
  const int seg = base - kHalo + g * kS;  // global row of buf[0] (may be <0)

  float buf[kS];
  float ky[kS];  // kC2 * y (pre-scaled)
#pragma unroll
  for (int r = 0; r < kS; ++r) {
    const int gi = seg + r;
    float v;
    if (EDGE) {
      v = (gi >= 0 && gi < kN) ? y[gi * 8 + b] : 0.0f;
    } else {
      v = y[gi * 8 + b];
    }
    buf[r] = v;
    ky[r] = kC2 * v;
  }

  for (int s = 0; s < kSweeps; ++s) {
    const int p = s & 1;
    // Publish this sweep's OLD segment-boundary values as float2 (b64 DS ops).
    const float2 ha = make_float2(buf[0], buf[1]);
    const float2 hb = make_float2(buf[kS - 2], buf[kS - 1]);
    hA[p][tid] = ha;
    hB[p][tid] = hb;
    __syncthreads();
    float om2 = 0.0f, om1 = 0.0f, hp1 = 0.0f, hp2 = 0.0f;
    if (g > 0) {
      const float2 t = hB[p][tid - 8];  // old rows seg-2, seg-1
      om2 = t.x;
      om1 = t.y;
    }
    if (g < kGroups - 1) {
      const float2 t = hA[p][tid + 8];  // old rows seg+kS, seg+kS+1
      hp1 = t.x;
      hp2 = t.y;
    }

    auto upd = [&](int r, float a2, float a1, float c, float d1,
                   float d2) -> float {
      if (EDGE) {
        const int gi = seg + r;
        const int lr = g * kS + r;
        float lap = a2 - 4.0f * a1 + 6.0f * c - 4.0f * d1 + d2;
        if (gi == 1) lap = -2.0f * a1 + 5.0f * c - 4.0f * d1 + d2;
        const float t = fmaf(-kC2, c, c) + ky[r];
        const float nv = fmaf(-kC1, lap, t);
        const bool frozen =
            (gi <= 0) || (gi >= kN - 2) || (lr < 2) || (lr >= kTot - 2);
        return frozen ? c : nv;
      } else {
        // 5 VALU ops, branch-free.
        float nv = fmaf(kCC, c, ky[r]);
        nv = fmaf(k4C1, a1 + d1, nv);
        nv = fmaf(-kC1, a2 + d2, nv);
        return nv;
      }
    };

    // In-place Jacobi with a 2-deep old-value window (om2, om1).
#pragma unroll
    for (int r = 0; r < kS - 2; ++r) {
      const float o0 = buf[r];
      const float nv = upd(r, om2, om1, o0, buf[r + 1], buf[r + 2]);
      buf[r] = nv;
      om2 = om1;
      om1 = o0;
    }
    {  // r = kS-2 (reads one halo value)
      const float o0 = buf[kS - 2];
      const float nv = upd(kS - 2, om2, om1, o0, buf[kS - 1], hp1);
      buf[kS - 2] = nv;
      om2 = om1;
      om1 = o0;
    }
    {  // r = kS-1 (reads two halo values)
      const float o0 = buf[kS - 1];
      const float nv = upd(kS - 1, om2, om1, o0, hp1, hp2);
      buf[kS - 1] = nv;
    }
    if (!EDGE) {
      // Freeze the 2 region-edge rows on each side (restore sweep-start old
      // values). Garbage from here propagates 2 rows/sweep -> 64 rows = the
      // discarded halo.
      if (g == 0) {
        buf[0] = ha.x;
        buf[1] = ha.y;
      }
      if (g == kGroups - 1) {
        buf[kS - 2] = hb.x;
        buf[kS - 1] = hb.y;
      }
    }
  }

  // Store only the valid 1024-row window.
#pragma unroll
  for (int r = 0; r < kS; ++r) {
    const int lr = g * kS + r;
    if (lr >= kHalo && lr < kHalo + kTile) {
      out[(seg + r) * 8 + b] = buf[r];
    }
  }
}

__global__ __launch_bounds__(kThreads, 6) void biharm_kernel(
    const float* __restrict__ y, float* __restrict__ out) {
  __shared__ float2 hA[2][kThreads];  // (buf[0], buf[1]) per thread
  __shared__ float2 hB[2][kThreads];  // (buf[kS-2], buf[kS-1]) per thread
  // Branch is block-uniform -> __syncthreads inside is safe.
  if (blockIdx.x == 0 || blockIdx.x == (int)gridDim.x - 1) {
    run_body<true>(y, out, hA, hB);
  } else {
    run_body<false>(y, out, hA, hB);
  }
}

extern "C" void kernel_launch(void* const* d_in, const int* in_sizes, int n_in,
                              void* d_out, int out_size, void* d_ws,
                              size_t ws_size, hipStream_t stream) {
  const float* yp = (const float*)d_in[0];
  float* outp = (float*)d_out;
  biharm_kernel<<<dim3(kN / kTile), dim3(kThreads), 0, stream>>>(yp, outp);
}

// Round 4
// 122.396 us; speedup vs baseline: 1.2470x; 1.0729x over previous
//
#include <hip/hip_runtime.h>

// Biharmonic Jacobi relaxation, 32 sweeps, one kernel, temporal blocking in
// registers.
//
// R4 changes vs R3:
//  - Discovered (R1-R3 CSVs): allocator splits the unified VGPR budget 50/50
//    arch/AGPR (128->64, 64->32, 80->40). So request budget 128 via
//    __launch_bounds__(512, 4) -> 64 arch VGPRs, which the whole state fits
//    in. Kills both the AGPR copy traffic and the residual scratch spills
//    (R3 WRITE_SIZE 49 MB vs 32 MB output).
//  - Packed fp32: each thread owns a COLUMN PAIR (4 pairs x 128 segments,
//    kS=9 rows). State is float2 (ext_vector) -> v_pk_fma_f32/v_pk_add_f32
//    halve VALU instruction count (5 packed ops per 2 element updates).
//    All boundary predicates are row-based -> uniform across the pair.
//  - Halo = float4 LDS planes (rows {0,1} / {kS-2,kS-1} x 2 cols), b128 DS,
//    stride-16 tid-indexed = conflict-free.

typedef float v2f __attribute__((ext_vector_type(2)));

namespace {
constexpr int kN = 1048576;
constexpr int kSweeps = 32;              // NUM_ITERATION + 1
constexpr int kTile = 1024;              // output rows per block
constexpr int kHalo = 64;                // 2 rows/sweep * 32 sweeps
constexpr int kTot = kTile + 2 * kHalo;  // 1152 region rows
constexpr int kThreads = 512;
constexpr int kPairs = 4;                // column pairs (B=8)
constexpr int kGroups = kThreads / kPairs;  // 128 row segments
constexpr int kS = kTot / kGroups;          // 9 rows per thread
constexpr float kC1 = 0.005f;               // ni * (1 - beta)
constexpr float kC2 = 0.005f;               // ni * beta
constexpr float kCC = 1.0f - 6.0f * kC1 - kC2;  // 0.965
constexpr float k4C1 = 4.0f * kC1;              // 0.02
}  // namespace

template <bool EDGE>
__device__ __forceinline__ void run_body(const v2f* __restrict__ y2,
                                         v2f* __restrict__ out2,
                                         float4 (*hA)[kThreads],
                                         float4 (*hB)[kThreads]) {
  const int tid = (int)threadIdx.x;
  const int cp = tid & (kPairs - 1);  // column pair (cols 2cp, 2cp+1)
  const int g = tid >> 2;             // row segment
  const int base = (int)blockIdx.x * kTile;
  const int seg = base - kHalo + g * kS;  // global row of buf[0] (may be <0)

  v2f buf[kS];
  v2f ky[kS];  // kC2 * y (pre-scaled)
#pragma unroll
  for (int r = 0; r < kS; ++r) {
    const int gi = seg + r;
    v2f v;
    if (EDGE) {
      v = (gi >= 0 && gi < kN) ? y2[gi * 4 + cp] : (v2f){0.0f, 0.0f};
    } else {
      v = y2[gi * 4 + cp];
    }
    buf[r] = v;
    ky[r] = kC2 * v;
  }

  const v2f vCC = {kCC, kCC};
  const v2f v4C1 = {k4C1, k4C1};
  const v2f vmC1 = {-kC1, -kC1};

  for (int s = 0; s < kSweeps; ++s) {
    const int p = s & 1;
    // Publish this sweep's OLD boundary rows (2 rows x 2 cols = float4).
    const float4 ha =
        make_float4(buf[0].x, buf[0].y, buf[1].x, buf[1].y);
    const float4 hb =
        make_float4(buf[kS - 2].x, buf[kS - 2].y, buf[kS - 1].x, buf[kS - 1].y);
    hA[p][tid] = ha;
    hB[p][tid] = hb;
    __syncthreads();
    v2f om2 = {0.0f, 0.0f}, om1 = {0.0f, 0.0f};
    v2f hp1 = {0.0f, 0.0f}, hp2 = {0.0f, 0.0f};
    if (g > 0) {
      const float4 t = hB[p][tid - kPairs];  // old rows seg-2, seg-1
      om2 = (v2f){t.x, t.y};
      om1 = (v2f){t.z, t.w};
    }
    if (g < kGroups - 1) {
      const float4 t = hA[p][tid + kPairs];  // old rows seg+kS, seg+kS+1
      hp1 = (v2f){t.x, t.y};
      hp2 = (v2f){t.z, t.w};
    }

    auto upd = [&](int r, v2f a2, v2f a1, v2f c, v2f d1, v2f d2) -> v2f {
      if (EDGE) {
        const int gi = seg + r;
        const int lr = g * kS + r;
        v2f lap = a2 - 4.0f * a1 + 6.0f * c - 4.0f * d1 + d2;
        if (gi == 1) lap = -2.0f * a1 + 5.0f * c - 4.0f * d1 + d2;
        const v2f t = (c - kC2 * c) + ky[r];
        const v2f nv = t - kC1 * lap;
        const bool frozen =
            (gi <= 0) || (gi >= kN - 2) || (lr < 2) || (lr >= kTot - 2);
        return frozen ? c : nv;
      } else {
        // 5 packed VALU ops for 2 element-updates.
        v2f nv = __builtin_elementwise_fma(vCC, c, ky[r]);
        nv = __builtin_elementwise_fma(v4C1, a1 + d1, nv);
        nv = __builtin_elementwise_fma(vmC1, a2 + d2, nv);
        return nv;
      }
    };

    // In-place Jacobi with a 2-deep old-value window (om2, om1).
#pragma unroll
    for (int r = 0; r < kS - 2; ++r) {
      const v2f o0 = buf[r];
      const v2f nv = upd(r, om2, om1, o0, buf[r + 1], buf[r + 2]);
      buf[r] = nv;
      om2 = om1;
      om1 = o0;
    }
    {  // r = kS-2 (reads one halo row)
      const v2f o0 = buf[kS - 2];
      const v2f nv = upd(kS - 2, om2, om1, o0, buf[kS - 1], hp1);
      buf[kS - 2] = nv;
      om2 = om1;
      om1 = o0;
    }
    {  // r = kS-1 (reads two halo rows)
      const v2f o0 = buf[kS - 1];
      const v2f nv = upd(kS - 1, om2, om1, o0, hp1, hp2);
      buf[kS - 1] = nv;
    }
    if (!EDGE) {
      // Freeze the 2 region-edge rows on each side (restore sweep-start old
      // values). Garbage propagates 2 rows/sweep -> 64 rows = discarded halo.
      if (g == 0) {
        buf[0] = (v2f){ha.x, ha.y};
        buf[1] = (v2f){ha.z, ha.w};
      }
      if (g == kGroups - 1) {
        buf[kS - 2] = (v2f){hb.x, hb.y};
        buf[kS - 1] = (v2f){hb.z, hb.w};
      }
    }
  }

  // Store only the valid 1024-row window.
#pragma unroll
  for (int r = 0; r < kS; ++r) {
    const int lr = g * kS + r;
    if (lr >= kHalo && lr < kHalo + kTile) {
      out2[(seg + r) * 4 + cp] = buf[r];
    }
  }
}

__global__ __launch_bounds__(kThreads, 4) void biharm_kernel(
    const float* __restrict__ y, float* __restrict__ out) {
  __shared__ float4 hA[2][kThreads];  // rows {0,1} x col-pair, double-buffered
  __shared__ float4 hB[2][kThreads];  // rows {kS-2,kS-1} x col-pair
  const v2f* y2 = (const v2f*)y;
  v2f* out2 = (v2f*)out;
  // Branch is block-uniform -> __syncthreads inside is safe.
  if (blockIdx.x == 0 || blockIdx.x == (int)gridDim.x - 1) {
    run_body<true>(y2, out2, hA, hB);
  } else {
    run_body<false>(y2, out2, hA, hB);
  }
}

extern "C" void kernel_launch(void* const* d_in, const int* in_sizes, int n_in,
                              void* d_out, int out_size, void* d_ws,
                              size_t ws_size, hipStream_t stream) {
  const float* yp = (const float*)d_in[0];
  float* outp = (float*)d_out;
  biharm_kernel<<<dim3(kN / kTile), dim3(kThreads), 0, stream>>>(yp, outp);
}

// Round 6
// 120.870 us; speedup vs baseline: 1.2627x; 1.0126x over previous
//
#include <hip/hip_runtime.h>

// Biharmonic Jacobi relaxation, 32 sweeps, one kernel, temporal blocking in
// registers.
//
// R6 changes vs R5/R4:
//  - REVERT R5's inline-asm v_pk_* and amdgpu_waves_per_eu(4,4): first launch
//    was correct but graph replays diverged (post-timing absmax 2.79).
//    Back to plain compiler codegen that passed all tripwires in R2-R4.
//  - Allocator model from R1-R4 CSVs: it chases 8 waves/EU (64 unified
//    regs/lane) regardless of launch bounds, spilling overflow to AGPRs
//    (v_accvgpr shuffles on every access). Fix: make live state fit.
//    768 threads/block (192 segments x 4 column-pairs), kS=6 rows/thread:
//    buf[6]+ky[6] float2 = 24 regs + temps ~= 45-50 live < 64.
//  - Freeze region-edge rows via ky[r]*200 (rows are constant ~= y forever;
//    rounding delta confined to the discarded 64-row halo) -> no ha/hb
//    registers kept live across the sweep.

typedef float v2f __attribute__((ext_vector_type(2)));

namespace {
constexpr int kN = 1048576;
constexpr int kSweeps = 32;              // NUM_ITERATION + 1
constexpr int kTile = 1024;              // output rows per block
constexpr int kHalo = 64;                // 2 rows/sweep * 32 sweeps
constexpr int kTot = kTile + 2 * kHalo;  // 1152 region rows
constexpr int kThreads = 768;
constexpr int kPairs = 4;                   // column pairs (B=8)
constexpr int kGroups = kThreads / kPairs;  // 192 row segments
constexpr int kS = kTot / kGroups;          // 6 rows per thread
constexpr float kC1 = 0.005f;               // ni * (1 - beta)
constexpr float kC2 = 0.005f;               // ni * beta
constexpr float kCC = 1.0f - 6.0f * kC1 - kC2;  // 0.965
constexpr float k4C1 = 4.0f * kC1;              // 0.02
constexpr float kInv = 1.0f / kC2;              // 200.0f
}  // namespace

template <bool EDGE>
__device__ __forceinline__ void run_body(const v2f* __restrict__ y2,
                                         v2f* __restrict__ out2,
                                         float4 (*hA)[kThreads],
                                         float4 (*hB)[kThreads]) {
  const int tid = (int)threadIdx.x;
  const int cp = tid & (kPairs - 1);  // column pair (cols 2cp, 2cp+1)
  const int g = tid >> 2;             // row segment
  const int base = (int)blockIdx.x * kTile;
  const int seg = base - kHalo + g * kS;  // global row of buf[0] (may be <0)

  v2f buf[kS];
  v2f ky[kS];  // kC2 * y (pre-scaled)
#pragma unroll
  for (int r = 0; r < kS; ++r) {
    const int gi = seg + r;
    v2f v;
    if (EDGE) {
      v = (gi >= 0 && gi < kN) ? y2[gi * 4 + cp] : (v2f){0.0f, 0.0f};
    } else {
      v = y2[gi * 4 + cp];
    }
    buf[r] = v;
    ky[r] = kC2 * v;
  }

  const v2f vCC = {kCC, kCC};
  const v2f v4C1 = {k4C1, k4C1};
  const v2f vmC1 = {-kC1, -kC1};

  for (int s = 0; s < kSweeps; ++s) {
    const int p = s & 1;
    // Publish this sweep's OLD boundary rows (2 rows x 2 cols = float4).
    hA[p][tid] = make_float4(buf[0].x, buf[0].y, buf[1].x, buf[1].y);
    hB[p][tid] =
        make_float4(buf[kS - 2].x, buf[kS - 2].y, buf[kS - 1].x, buf[kS - 1].y);
    __syncthreads();
    v2f om2 = {0.0f, 0.0f}, om1 = {0.0f, 0.0f};
    v2f hp1 = {0.0f, 0.0f}, hp2 = {0.0f, 0.0f};
    if (g > 0) {
      const float4 t = hB[p][tid - kPairs];  // old rows seg-2, seg-1
      om2 = (v2f){t.x, t.y};
      om1 = (v2f){t.z, t.w};
    }
    if (g < kGroups - 1) {
      const float4 t = hA[p][tid + kPairs];  // old rows seg+kS, seg+kS+1
      hp1 = (v2f){t.x, t.y};
      hp2 = (v2f){t.z, t.w};
    }

    auto upd = [&](int r, v2f a2, v2f a1, v2f c, v2f d1, v2f d2) -> v2f {
      if (EDGE) {
        const int gi = seg + r;
        const int lr = g * kS + r;
        v2f lap = a2 - 4.0f * a1 + 6.0f * c - 4.0f * d1 + d2;
        if (gi == 1) lap = -2.0f * a1 + 5.0f * c - 4.0f * d1 + d2;
        const v2f t = (c - kC2 * c) + ky[r];
        const v2f nv = t - kC1 * lap;
        const bool frozen =
            (gi <= 0) || (gi >= kN - 2) || (lr < 2) || (lr >= kTot - 2);
        return frozen ? c : nv;
      } else {
        // 5 VALU ops (packed if the compiler chooses) per 2 element-updates.
        v2f nv = __builtin_elementwise_fma(vCC, c, ky[r]);
        nv = __builtin_elementwise_fma(v4C1, a1 + d1, nv);
        nv = __builtin_elementwise_fma(vmC1, a2 + d2, nv);
        return nv;
      }
    };

    // In-place Jacobi with a 2-deep old-value window (om2, om1).
#pragma unroll
    for (int r = 0; r < kS - 2; ++r) {
      const v2f o0 = buf[r];
      const v2f nv = upd(r, om2, om1, o0, buf[r + 1], buf[r + 2]);
      buf[r] = nv;
      om2 = om1;
      om1 = o0;
    }
    {  // r = kS-2 (reads one halo row)
      const v2f o0 = buf[kS - 2];
      const v2f nv = upd(kS - 2, om2, om1, o0, buf[kS - 1], hp1);
      buf[kS - 2] = nv;
      om2 = om1;
      om1 = o0;
    }
    {  // r = kS-1 (reads two halo rows)
      const v2f o0 = buf[kS - 1];
      const v2f nv = upd(kS - 1, om2, om1, o0, hp1, hp2);
      buf[kS - 1] = nv;
    }
    if (!EDGE) {
      // Freeze the 2 region-edge rows on each side. They are constant
      // (~= y) for the whole kernel, so rebuild from ky instead of keeping
      // sweep-start copies live. Rounding delta and freeze-wrongness both
      // propagate 2 rows/sweep -> 64 rows = exactly the discarded halo.
      if (g == 0) {
        buf[0] = ky[0] * kInv;
        buf[1] = ky[1] * kInv;
      }
      if (g == kGroups - 1) {
        buf[kS - 2] = ky[kS - 2] * kInv;
        buf[kS - 1] = ky[kS - 1] * kInv;
      }
    }
  }

  // Store only the valid 1024-row window.
#pragma unroll
  for (int r = 0; r < kS; ++r) {
    const int lr = g * kS + r;
    if (lr >= kHalo && lr < kHalo + kTile) {
      out2[(seg + r) * 4 + cp] = buf[r];
    }
  }
}

__global__ __launch_bounds__(kThreads) void biharm_kernel(
    const float* __restrict__ y, float* __restrict__ out) {
  __shared__ float4 hA[2][kThreads];  // rows {0,1} x col-pair, double-buffered
  __shared__ float4 hB[2][kThreads];  // rows {kS-2,kS-1} x col-pair
  const v2f* y2 = (const v2f*)y;
  v2f* out2 = (v2f*)out;
  // Branch is block-uniform -> __syncthreads inside is safe.
  if (blockIdx.x == 0 || blockIdx.x == (int)gridDim.x - 1) {
    run_body<true>(y2, out2, hA, hB);
  } else {
    run_body<false>(y2, out2, hA, hB);
  }
}

extern "C" void kernel_launch(void* const* d_in, const int* in_sizes, int n_in,
                              void* d_out, int out_size, void* d_ws,
                              size_t ws_size, hipStream_t stream) {
  const float* yp = (const float*)d_in[0];
  float* outp = (float*)d_out;
  biharm_kernel<<<dim3(kN / kTile), dim3(kThreads), 0, stream>>>(yp, outp);
}

// Round 7
// 118.842 us; speedup vs baseline: 1.2843x; 1.0171x over previous
//
#include <hip/hip_runtime.h>

// Biharmonic Jacobi relaxation, 32 sweeps, one kernel, temporal blocking in
// registers — R7: BARRIER-FREE sweep loop via intra-wave shuffles.
//
// R6 post-mortem: spills gone (WRITE=32MB exactly) yet dur stuck ~60us,
// VALUBusy 56%. The 44% idle = 32 per-sweep __syncthreads convoys; the VALU
// excess = float4<->float2 marshalling for the LDS halo. Fix both by mapping
// segment-neighbors to adjacent LANES:
//   wave w  <-> column w (8 waves = 8 cols, 512 threads)
//   lane l  <-> rows 18l..18l+17 of the 1152-row block region (64*18=1152)
// Per sweep the halo is 4 __shfl_up/down(.,1) — no LDS, no barrier. Lane 0 /
// lane 63 rows are the frozen region edges (rebuilt as ky*200, validated R6);
// wave-edge shuffle junk is consumed only by frozen rows.
// Global I/O for lane-owns-column would be stride-576B scattered, so load and
// store go through a pad-9 LDS transpose (41.5 KB; bank pattern 2l+9r+w =
// 2-way aliasing = free per m136). 3 barriers total for the whole kernel.

namespace {
constexpr int kN = 1048576;
constexpr int kSweeps = 32;              // NUM_ITERATION + 1
constexpr int kTile = 1024;              // output rows per block
constexpr int kHalo = 64;                // 2 rows/sweep * 32 sweeps
constexpr int kTot = kTile + 2 * kHalo;  // 1152 region rows
constexpr int kThreads = 512;            // 8 waves
constexpr int kS = kTot / 64;            // 18 rows per lane
constexpr int kPad = 9;                  // LDS row stride (floats), pad +1
constexpr float kC1 = 0.005f;            // ni * (1 - beta)
constexpr float kC2 = 0.005f;            // ni * beta
constexpr float kCC = 1.0f - 6.0f * kC1 - kC2;  // 0.965
constexpr float k4C1 = 4.0f * kC1;              // 0.02
constexpr float kInv = 1.0f / kC2;              // 200.0f
}  // namespace

template <bool EDGE>
__device__ __forceinline__ void run_body(const float* __restrict__ y,
                                         float* __restrict__ out,
                                         float* __restrict__ st) {
  const int tid = (int)threadIdx.x;
  const int w = tid >> 6;  // wave id == column
  const int l = tid & 63;  // lane == row segment (rows kS*l .. kS*l+17)
  const long base = (long)blockIdx.x * kTile - kHalo;  // region row 0 (global)

  // ---- Stage y into LDS, coalesced float2 global reads, padded rows.
#pragma unroll
  for (int k = 0; k < 9; ++k) {
    const int idx = (tid + k * kThreads) * 2;  // 9216 floats / block region
    const int r = idx >> 3, c = idx & 7;       // c is even -> float2 in-row
    float2 v;
    if (EDGE) {
      const long gi = base + r;
      if (gi >= 0 && gi < kN) {
        v = *(const float2*)&y[gi * 8 + c];
      } else {
        v = make_float2(0.0f, 0.0f);
      }
    } else {
      v = *(const float2*)&y[(base + r) * 8 + c];
    }
    st[r * kPad + c] = v.x;
    st[r * kPad + c + 1] = v.y;
  }
  __syncthreads();

  // ---- Fragment load: lane's 18 rows of its column (2-way banks = free).
  float buf[kS];
  float ky[kS];
#pragma unroll
  for (int r = 0; r < kS; ++r) {
    const float v = st[(l * kS + r) * kPad + w];
    buf[r] = v;
    ky[r] = kC2 * v;
  }

  // ---- 32 sweeps, NO barriers. Halo = 4 shuffles per sweep.
  for (int s = 0; s < kSweeps; ++s) {
    const float om2_0 = __shfl_up(buf[kS - 2], 1, 64);  // old row -2
    const float om1_0 = __shfl_up(buf[kS - 1], 1, 64);  // old row -1
    const float hp1 = __shfl_down(buf[0], 1, 64);       // old row +kS
    const float hp2 = __shfl_down(buf[1], 1, 64);       // old row +kS+1
    float om2 = om2_0, om1 = om1_0;
#pragma unroll
    for (int r = 0; r < kS; ++r) {
      const float o0 = buf[r];
      const float d1 = (r < kS - 1) ? buf[r + 1] : hp1;
      const float d2 = (r < kS - 2) ? buf[r + 2] : ((r == kS - 2) ? hp1 : hp2);
      float nv;
      if (EDGE) {
        const long gi = base + l * kS + r;
        const int lr = l * kS + r;
        float lap = om2 - 4.0f * om1 + 6.0f * o0 - 4.0f * d1 + d2;
        if (gi == 1) lap = -2.0f * om1 + 5.0f * o0 - 4.0f * d1 + d2;
        const float t = fmaf(-kC2, o0, o0) + ky[r];
        nv = fmaf(-kC1, lap, t);
        const bool frozen =
            (gi <= 0) || (gi >= kN - 2) || (lr < 2) || (lr >= kTot - 2);
        if (frozen) nv = o0;
      } else {
        // 5 VALU ops per update, branch-free.
        nv = fmaf(kCC, o0, ky[r]);
        nv = fmaf(k4C1, om1 + d1, nv);
        nv = fmaf(-kC1, om2 + d2, nv);
      }
      buf[r] = nv;
      om2 = om1;
      om1 = o0;
    }
    if (!EDGE) {
      // Frozen region-edge rows: constant ~= y forever; rebuild from ky.
      // Wave-edge shuffle junk is only ever consumed by these rows' stencils
      // through the om window, which re-reads the frozen (correct) values.
      if (l == 0) {
        buf[0] = ky[0] * kInv;
        buf[1] = ky[1] * kInv;
      }
      if (l == 63) {
        buf[kS - 2] = ky[kS - 2] * kInv;
        buf[kS - 1] = ky[kS - 1] * kInv;
      }
    }
  }

  // ---- Stage result back through LDS (transpose), coalesced float2 stores.
  __syncthreads();  // all fragment reads of st are done before overwrite
#pragma unroll
  for (int r = 0; r < kS; ++r) {
    st[(l * kS + r) * kPad + w] = buf[r];
  }
  __syncthreads();
#pragma unroll
  for (int k = 0; k < 8; ++k) {
    const int idx = (tid + k * kThreads) * 2;  // 8192 valid floats / block
    const int r = idx >> 3, c = idx & 7;
    float2 v;
    v.x = st[(kHalo + r) * kPad + c];
    v.y = st[(kHalo + r) * kPad + c + 1];
    *(float2*)&out[(base + kHalo + r) * 8 + c] = v;
  }
}

__global__ __launch_bounds__(kThreads) void biharm_kernel(
    const float* __restrict__ y, float* __restrict__ out) {
  __shared__ float st[kTot * kPad];  // 41472 B staging/transpose buffer
  // Branch is block-uniform -> __syncthreads inside is safe.
  if (blockIdx.x == 0 || blockIdx.x == (int)gridDim.x - 1) {
    run_body<true>(y, out, st);
  } else {
    run_body<false>(y, out, st);
  }
}

extern "C" void kernel_launch(void* const* d_in, const int* in_sizes, int n_in,
                              void* d_out, int out_size, void* d_ws,
                              size_t ws_size, hipStream_t stream) {
  const float* yp = (const float*)d_in[0];
  float* outp = (float*)d_out;
  biharm_kernel<<<dim3(kN / kTile), dim3(kThreads), 0, stream>>>(yp, outp);
}

// Round 8
// 101.759 us; speedup vs baseline: 1.4999x; 1.1679x over previous
//
#include <hip/hip_runtime.h>

// R8: replace the 32-sweep Jacobi iteration with ONE 129-tap convolution.
//
// R4/R6/R7 post-mortem: three structurally different sweep kernels (LDS-halo
// +32 barriers; fewer regs; barrier-free shuffle halo) ALL land at 58-61 us
// with ~31 us VALU busy -> the iterative structure itself is the floor.
// The update is linear & shift-invariant: out = (A^32 + c2*sum A^k) y = W*y,
// W a fixed symmetric 129-tap kernel (computed at compile time in double).
// Interior rows i in [66, N-67] never see a boundary-special row through the
// 32-sweep dependency cone -> plain convolution is EXACT there. Blocks 0 and
// 2047 keep the validated R7 literal-sweep path for global boundaries.
//
// Conv block: 512 output rows, 640 input rows staged col-major in LDS
// (col stride 652; 652 % 32 == 12 -> b128 reads spread 8 words/bank =
// conflict-free). Thread = 1 col x 8 consecutive rows: 34 ds_read_b128 +
// 1032 independent FMAs into acc[8]. No sweep loop, 1 barrier, ~20 VGPRs.

namespace {
constexpr int kN = 1048576;
constexpr int kSweeps = 32;             // NUM_ITERATION + 1
constexpr int kTile = 512;              // output rows per block
constexpr int kHalo = 64;               // conv support per side = 2*32
constexpr int kReg = kTile + 2 * kHalo; // 640 region rows
constexpr int kThreads = 512;
constexpr int kColS = 652;              // LDS col stride (floats), %32==12
constexpr int kSmemFloats = 5760;       // max(8*652=5216, 640*9=5760)
// Edge (literal sweep) constants — validated in R6/R7:
constexpr int kS = kReg / 64;           // 10 rows per lane
constexpr int kPad = 9;                 // row-major pad for edge staging
constexpr float kC1 = 0.005f;           // ni * (1 - beta)
constexpr float kC2 = 0.005f;           // ni * beta
constexpr float kCC = 1.0f - 6.0f * kC1 - kC2;  // 0.965
constexpr float k4C1 = 4.0f * kC1;              // 0.02
constexpr float kInv = 1.0f / kC2;              // 200.0f

// ---- Compile-time 129-tap weights: W = A^32 + c2 * sum_{k=0}^{31} A^k ----
struct WF {
  float w[129];
};
constexpr WF make_w() {
  const double ni = (double)0.01f;
  const double c1 = ni * 0.5;
  const double c2 = ni * 0.5;
  double p[129] = {};  // current A^k row (symmetric operator)
  double s[129] = {};  // sum of A^k, k=0..31
  p[64] = 1.0;
  for (int k = 0; k < kSweeps; ++k) {
    for (int i = 0; i < 129; ++i) s[i] += p[i];
    double q[129] = {};
    for (int i = 0; i < 129; ++i) {
      const double m2 = (i > 1) ? p[i - 2] : 0.0;
      const double m1 = (i > 0) ? p[i - 1] : 0.0;
      const double p1 = (i < 128) ? p[i + 1] : 0.0;
      const double p2 = (i < 127) ? p[i + 2] : 0.0;
      const double lap = m2 - 4.0 * m1 + 6.0 * p[i] - 4.0 * p1 + p2;
      q[i] = p[i] - c1 * lap - c2 * p[i];
    }
    for (int i = 0; i < 129; ++i) p[i] = q[i];
  }
  WF f{};
  for (int i = 0; i < 129; ++i) f.w[i] = (float)(p[i] + c2 * s[i]);
  return f;
}
constexpr WF kWT = make_w();
}  // namespace

// ---------------- Interior: direct 129-tap convolution ----------------
__device__ __forceinline__ void run_conv(const float* __restrict__ y,
                                         float* __restrict__ out,
                                         float* __restrict__ sm) {
  const int tid = (int)threadIdx.x;
  const int c = tid & 7;   // column
  const int g = tid >> 3;  // row group (8 rows each)
  const long base = (long)blockIdx.x * kTile;  // output rows [base, base+512)

  // Stage region rows [base-64, base+576) col-major into LDS.
#pragma unroll
  for (int k = 0; k < 5; ++k) {
    const int idx = tid + k * kThreads;     // 2560 float2
    const int r = idx >> 2;                 // region row
    const int cp = (idx & 3) * 2;           // even column
    const float2 v = *(const float2*)&y[(base - kHalo + r) * 8 + cp];
    sm[cp * kColS + r] = v.x;
    sm[(cp + 1) * kColS + r] = v.y;
  }
  __syncthreads();

  float acc[8] = {0.f, 0.f, 0.f, 0.f, 0.f, 0.f, 0.f, 0.f};
  const int r0 = g * 8;  // thread's outputs: region rows 64+r0 .. 64+r0+7
  const float* col = &sm[c * kColS + r0];  // input window rows r0..r0+135
#pragma unroll
  for (int q4 = 0; q4 < 34; ++q4) {
    const float4 x = *(const float4*)&col[4 * q4];
    const float xv[4] = {x.x, x.y, x.z, x.w};
#pragma unroll
    for (int i = 0; i < 4; ++i) {
      const int mm = 4 * q4 + i;
#pragma unroll
      for (int k = 0; k < 8; ++k) {
        const int j = mm - 64 - k;  // tap index
        if (j >= -64 && j <= 64) {
          acc[k] = fmaf(kWT.w[j + 64], xv[i], acc[k]);
        }
      }
    }
  }

#pragma unroll
  for (int k = 0; k < 8; ++k) {
    out[(base + r0 + k) * 8 + c] = acc[k];
  }
}

// ------------- Edge blocks: literal 32 sweeps (R7 path, kS=10) -------------
__device__ __forceinline__ void run_edge(const float* __restrict__ y,
                                         float* __restrict__ out,
                                         float* __restrict__ st) {
  const int tid = (int)threadIdx.x;
  const int w = tid >> 6;  // wave id == column
  const int l = tid & 63;  // lane == row segment (rows kS*l .. kS*l+9)
  const long base = (long)blockIdx.x * kTile - kHalo;  // region row 0

  // Stage y row-major (pad-9), guarded.
#pragma unroll
  for (int k = 0; k < 5; ++k) {
    const int idx = (tid + k * kThreads) * 2;  // 5120 floats
    const int r = idx >> 3, c = idx & 7;
    const long gi = base + r;
    float2 v = make_float2(0.0f, 0.0f);
    if (gi >= 0 && gi < kN) v = *(const float2*)&y[gi * 8 + c];
    st[r * kPad + c] = v.x;
    st[r * kPad + c + 1] = v.y;
  }
  __syncthreads();

  float buf[kS];
  float ky[kS];
#pragma unroll
  for (int r = 0; r < kS; ++r) {
    const float v = st[(l * kS + r) * kPad + w];
    buf[r] = v;
    ky[r] = kC2 * v;
  }

  for (int s = 0; s < kSweeps; ++s) {
    const float om2_0 = __shfl_up(buf[kS - 2], 1, 64);
    const float om1_0 = __shfl_up(buf[kS - 1], 1, 64);
    const float hp1 = __shfl_down(buf[0], 1, 64);
    const float hp2 = __shfl_down(buf[1], 1, 64);
    float om2 = om2_0, om1 = om1_0;
#pragma unroll
    for (int r = 0; r < kS; ++r) {
      const float o0 = buf[r];
      const float d1 = (r < kS - 1) ? buf[r + 1] : hp1;
      const float d2 = (r < kS - 2) ? buf[r + 2] : ((r == kS - 2) ? hp1 : hp2);
      const long gi = base + l * kS + r;
      const int lr = l * kS + r;
      float lap = om2 - 4.0f * om1 + 6.0f * o0 - 4.0f * d1 + d2;
      if (gi == 1) lap = -2.0f * om1 + 5.0f * o0 - 4.0f * d1 + d2;
      const float t = fmaf(-kC2, o0, o0) + ky[r];
      float nv = fmaf(-kC1, lap, t);
      const bool frozen =
          (gi <= 0) || (gi >= kN - 2) || (lr < 2) || (lr >= kReg - 2);
      if (frozen) nv = o0;
      buf[r] = nv;
      om2 = om1;
      om1 = o0;
    }
  }

  __syncthreads();
#pragma unroll
  for (int r = 0; r < kS; ++r) {
    st[(l * kS + r) * kPad + w] = buf[r];
  }
  __syncthreads();
#pragma unroll
  for (int k = 0; k < 4; ++k) {
    const int idx = (tid + k * kThreads) * 2;  // 4096 valid floats
    const int r = idx >> 3, c = idx & 7;
    float2 v;
    v.x = st[(kHalo + r) * kPad + c];
    v.y = st[(kHalo + r) * kPad + c + 1];
    *(float2*)&out[(base + kHalo + r) * 8 + c] = v;
  }
}

__global__ __launch_bounds__(kThreads) void biharm_kernel(
    const float* __restrict__ y, float* __restrict__ out) {
  __shared__ __align__(16) float sm[kSmemFloats];  // 23,040 B
  // Branch is block-uniform -> __syncthreads inside is safe.
  if (blockIdx.x == 0 || blockIdx.x == (int)gridDim.x - 1) {
    run_edge(y, out, sm);
  } else {
    run_conv(y, out, sm);
  }
}

extern "C" void kernel_launch(void* const* d_in, const int* in_sizes, int n_in,
                              void* d_out, int out_size, void* d_ws,
                              size_t ws_size, hipStream_t stream) {
  const float* yp = (const float*)d_in[0];
  float* outp = (float*)d_out;
  biharm_kernel<<<dim3(kN / kTile), dim3(kThreads), 0, stream>>>(yp, outp);
}

// Round 9
// 95.255 us; speedup vs baseline: 1.6023x; 1.0683x over previous
//
#include <hip/hip_runtime.h>

// R9: truncated 25-tap convolution (radius 12) replacing R8's exact 129-tap.
//
// R8 proved the conv structure: kernel fell from ~60us (iterative floor,
// R4/R6/R7 all identical) to below the harness's own 43us poison-fills.
// The exact kernel W = A^32 + c2*sum A^k has taps decaying combinatorially
// (A: center .965, +-1: .02, +-2: -.005): |w_13| ~ 7e-9, sum_{|j|>12}|w_j|
// ~ 1e-8. Truncation to +-12 adds ~5e-8 absolute error vs the 7.06e-2
// threshold (existing fp32 rounding error: 7.8e-3). Cuts per-thread FMAs
// 1032 -> 200, input window 136 -> 32 rows, halo 64 -> 16 rows.
// Interior rows never see boundary-special rows through the (full) 64-row
// cone; blocks 0 / 2047 keep the R8-validated literal-sweep path verbatim.

namespace {
constexpr int kN = 1048576;
constexpr int kSweeps = 32;   // NUM_ITERATION + 1
constexpr int kTile = 512;    // output rows per block
constexpr int kThreads = 512;

// --- conv path ---
constexpr int kR = 12;                   // truncated tap radius
constexpr int kHaloC = 16;               // staged halo (>= kR, float4-friendly)
constexpr int kRegC = kTile + 2 * kHaloC;  // 544 region rows
constexpr int kColS = 556;               // LDS col stride (floats), %32==12

// --- edge (literal sweep) path, validated R7/R8 ---
constexpr int kHaloE = 64;                  // 2 rows/sweep * 32 sweeps
constexpr int kRegE = kTile + 2 * kHaloE;   // 640 region rows
constexpr int kS = kRegE / 64;              // 10 rows per lane
constexpr int kPad = 9;                     // row-major pad for edge staging
constexpr float kC1 = 0.005f;               // ni * (1 - beta)
constexpr float kC2 = 0.005f;               // ni * beta

constexpr int kSmemFloats = 5760;  // max(8*556=4448, 640*9=5760)

// ---- Compile-time weights: W = A^32 + c2 * sum_{k=0}^{31} A^k, center 25 ----
struct WF {
  float w[2 * kR + 1];
};
constexpr WF make_w() {
  const double ni = (double)0.01f;
  const double c1 = ni * 0.5;
  const double c2 = ni * 0.5;
  double p[129] = {};  // current A^k row (symmetric operator)
  double s[129] = {};  // sum of A^k, k=0..31
  p[64] = 1.0;
  for (int k = 0; k < kSweeps; ++k) {
    for (int i = 0; i < 129; ++i) s[i] += p[i];
    double q[129] = {};
    for (int i = 0; i < 129; ++i) {
      const double m2 = (i > 1) ? p[i - 2] : 0.0;
      const double m1 = (i > 0) ? p[i - 1] : 0.0;
      const double p1 = (i < 128) ? p[i + 1] : 0.0;
      const double p2 = (i < 127) ? p[i + 2] : 0.0;
      const double lap = m2 - 4.0 * m1 + 6.0 * p[i] - 4.0 * p1 + p2;
      q[i] = p[i] - c1 * lap - c2 * p[i];
    }
    for (int i = 0; i < 129; ++i) p[i] = q[i];
  }
  WF f{};
  for (int i = 0; i < 2 * kR + 1; ++i) {
    f.w[i] = (float)(p[64 - kR + i] + c2 * s[64 - kR + i]);
  }
  return f;
}
constexpr WF kWT = make_w();
}  // namespace

// ---------------- Interior: 25-tap convolution ----------------
__device__ __forceinline__ void run_conv(const float* __restrict__ y,
                                         float* __restrict__ out,
                                         float* __restrict__ sm) {
  const int tid = (int)threadIdx.x;
  const int c = tid & 7;   // column
  const int g = tid >> 3;  // row group (8 rows each)
  const long base = (long)blockIdx.x * kTile;  // output rows [base, base+512)

  // Stage region rows [base-16, base+528) col-major, float4 global loads.
  // 544 rows * 8 cols = 4352 floats = 1088 float4.
#pragma unroll
  for (int k = 0; k < 3; ++k) {
    const int idx = tid + k * kThreads;
    if (idx < (kRegC * 8) / 4) {
      const int r = idx >> 1;            // region row
      const int cp = (idx & 1) * 4;      // column 0 or 4
      const float4 v = *(const float4*)&y[(base - kHaloC + r) * 8 + cp];
      sm[(cp + 0) * kColS + r] = v.x;
      sm[(cp + 1) * kColS + r] = v.y;
      sm[(cp + 2) * kColS + r] = v.z;
      sm[(cp + 3) * kColS + r] = v.w;
    }
  }
  __syncthreads();

  // Thread outputs: region rows 16+r0 .. 16+r0+7 (r0 = 8g).
  // Inputs needed: region rows r0+4 .. r0+35 (32 rows, float4-aligned).
  float acc[8] = {0.f, 0.f, 0.f, 0.f, 0.f, 0.f, 0.f, 0.f};
  const int r0 = g * 8;
  const float* col = &sm[c * kColS + r0 + 4];
#pragma unroll
  for (int q = 0; q < 8; ++q) {
    const float4 x = *(const float4*)&col[4 * q];
    const float xv[4] = {x.x, x.y, x.z, x.w};
#pragma unroll
    for (int i = 0; i < 4; ++i) {
      const int m = 4 * q + i;  // input = region row r0+4+m
#pragma unroll
      for (int k = 0; k < 8; ++k) {
        // tap index t = (r0+4+m) - (16+r0+k) = m-12-k, valid iff |t|<=12.
        if (m - k >= 0 && m - k <= 2 * kR) {
          acc[k] = fmaf(kWT.w[m - k], xv[i], acc[k]);
        }
      }
    }
  }

#pragma unroll
  for (int k = 0; k < 8; ++k) {
    out[(base + r0 + k) * 8 + c] = acc[k];
  }
}

// ------------- Edge blocks: literal 32 sweeps (R7/R8 path) -------------
__device__ __forceinline__ void run_edge(const float* __restrict__ y,
                                         float* __restrict__ out,
                                         float* __restrict__ st) {
  const int tid = (int)threadIdx.x;
  const int w = tid >> 6;  // wave id == column
  const int l = tid & 63;  // lane == row segment (rows kS*l .. kS*l+9)
  const long base = (long)blockIdx.x * kTile - kHaloE;  // region row 0

  // Stage y row-major (pad-9), guarded.
#pragma unroll
  for (int k = 0; k < 5; ++k) {
    const int idx = (tid + k * kThreads) * 2;  // 5120 floats = 640*8
    const int r = idx >> 3, c = idx & 7;
    const long gi = base + r;
    float2 v = make_float2(0.0f, 0.0f);
    if (gi >= 0 && gi < kN) v = *(const float2*)&y[gi * 8 + c];
    st[r * kPad + c] = v.x;
    st[r * kPad + c + 1] = v.y;
  }
  __syncthreads();

  float buf[kS];
  float ky[kS];
#pragma unroll
  for (int r = 0; r < kS; ++r) {
    const float v = st[(l * kS + r) * kPad + w];
    buf[r] = v;
    ky[r] = kC2 * v;
  }

  for (int s = 0; s < kSweeps; ++s) {
    const float om2_0 = __shfl_up(buf[kS - 2], 1, 64);
    const float om1_0 = __shfl_up(buf[kS - 1], 1, 64);
    const float hp1 = __shfl_down(buf[0], 1, 64);
    const float hp2 = __shfl_down(buf[1], 1, 64);
    float om2 = om2_0, om1 = om1_0;
#pragma unroll
    for (int r = 0; r < kS; ++r) {
      const float o0 = buf[r];
      const float d1 = (r < kS - 1) ? buf[r + 1] : hp1;
      const float d2 = (r < kS - 2) ? buf[r + 2] : ((r == kS - 2) ? hp1 : hp2);
      const long gi = base + l * kS + r;
      const int lr = l * kS + r;
      float lap = om2 - 4.0f * om1 + 6.0f * o0 - 4.0f * d1 + d2;
      if (gi == 1) lap = -2.0f * om1 + 5.0f * o0 - 4.0f * d1 + d2;
      const float t = fmaf(-kC2, o0, o0) + ky[r];
      float nv = fmaf(-kC1, lap, t);
      const bool frozen =
          (gi <= 0) || (gi >= kN - 2) || (lr < 2) || (lr >= kRegE - 2);
      if (frozen) nv = o0;
      buf[r] = nv;
      om2 = om1;
      om1 = o0;
    }
  }

  __syncthreads();
#pragma unroll
  for (int r = 0; r < kS; ++r) {
    st[(l * kS + r) * kPad + w] = buf[r];
  }
  __syncthreads();
#pragma unroll
  for (int k = 0; k < 4; ++k) {
    const int idx = (tid + k * kThreads) * 2;  // 4096 valid floats
    const int r = idx >> 3, c = idx & 7;
    float2 v;
    v.x = st[(kHaloE + r) * kPad + c];
    v.y = st[(kHaloE + r) * kPad + c + 1];
    *(float2*)&out[(base + kHaloE + r) * 8 + c] = v;
  }
}

__global__ __launch_bounds__(kThreads) void biharm_kernel(
    const float* __restrict__ y, float* __restrict__ out) {
  __shared__ __align__(16) float sm[kSmemFloats];  // 23,040 B
  // Branch is block-uniform -> __syncthreads inside is safe.
  if (blockIdx.x == 0 || blockIdx.x == (int)gridDim.x - 1) {
    run_edge(y, out, sm);
  } else {
    run_conv(y, out, sm);
  }
}

extern "C" void kernel_launch(void* const* d_in, const int* in_sizes, int n_in,
                              void* d_out, int out_size, void* d_ws,
                              size_t ws_size, hipStream_t stream) {
  const float* yp = (const float*)d_in[0];
  float* outp = (float*)d_out;
  biharm_kernel<<<dim3(kN / kTile), dim3(kThreads), 0, stream>>>(yp, outp);
}

// Round 10
// 89.735 us; speedup vs baseline: 1.7008x; 1.0615x over previous
//
#include <hip/hip_runtime.h>

// R10: 17-tap (radius-8) convolution, 1024-row conv tiles, coalesced float4
// epilogue through LDS.
//
// R9 post-mortem: kernel ~36us (bench 95.3 - ~59us fixed harness overhead)
// vs ~15us roofline (VALU 4 + LDS 4 + HBM 66MB ~10). Residual = per-block
// structure: 2048 small blocks (2 occupancy rounds, 2x halo staging),
// scattered scalar stores, 25 taps where 17 suffice numerically
// (sum_{|d|>8}|w_d| ~ 6e-5 -> output error ~3e-4 vs 7.06e-2 threshold).
//
// Grid = 1025: block 0 / 1024 = literal-sweep edge blocks (512 rows, the
// R8/R9-validated path, handles row-0 copy / row-1 one-sided / last-two-
// reset exactly); blocks 1..1023 = conv tiles of 1024 rows covering
// [512, N-512) — every output there is >= 66 rows from a boundary, so the
// (untruncated) conv is exact and truncation adds ~3e-4.

namespace {
constexpr int kN = 1048576;
constexpr int kSweeps = 32;  // NUM_ITERATION + 1
constexpr int kThreads = 512;

// --- conv path ---
constexpr int kR = 8;                       // tap radius (17 taps)
constexpr int kTileC = 1024;                // output rows per conv block
constexpr int kHaloC = 16;                  // staged halo (float4-friendly)
constexpr int kRegC = kTileC + 2 * kHaloC;  // 1056 region rows
constexpr int kColS = 1068;                 // LDS col stride (floats)

// --- edge (literal sweep) path, validated R7-R9 ---
constexpr int kTileE = 512;
constexpr int kHaloE = 64;                  // 2 rows/sweep * 32 sweeps
constexpr int kRegE = kTileE + 2 * kHaloE;  // 640 region rows
constexpr int kS = kRegE / 64;              // 10 rows per lane
constexpr int kPad = 9;                     // row-major pad for edge staging
constexpr float kC1 = 0.005f;               // ni * (1 - beta)
constexpr float kC2 = 0.005f;               // ni * beta

constexpr int kSmemFloats = 8 * kColS;  // 8544 floats = 34,176 B (>= 5760)

// ---- Compile-time weights: W = A^32 + c2 * sum_{k=0}^{31} A^k, center 17 ----
struct WF {
  float w[2 * kR + 1];
};
constexpr WF make_w() {
  const double ni = (double)0.01f;
  const double c1 = ni * 0.5;
  const double c2 = ni * 0.5;
  double p[129] = {};  // current A^k row (symmetric operator)
  double s[129] = {};  // sum of A^k, k=0..31
  p[64] = 1.0;
  for (int k = 0; k < kSweeps; ++k) {
    for (int i = 0; i < 129; ++i) s[i] += p[i];
    double q[129] = {};
    for (int i = 0; i < 129; ++i) {
      const double m2 = (i > 1) ? p[i - 2] : 0.0;
      const double m1 = (i > 0) ? p[i - 1] : 0.0;
      const double p1 = (i < 128) ? p[i + 1] : 0.0;
      const double p2 = (i < 127) ? p[i + 2] : 0.0;
      const double lap = m2 - 4.0 * m1 + 6.0 * p[i] - 4.0 * p1 + p2;
      q[i] = p[i] - c1 * lap - c2 * p[i];
    }
    for (int i = 0; i < 129; ++i) p[i] = q[i];
  }
  WF f{};
  for (int i = 0; i < 2 * kR + 1; ++i) {
    f.w[i] = (float)(p[64 - kR + i] + c2 * s[64 - kR + i]);
  }
  return f;
}
constexpr WF kWT = make_w();
}  // namespace

// ---------------- Interior: 17-tap convolution, 1024-row tile ----------------
__device__ __forceinline__ void run_conv(const float* __restrict__ y,
                                         float* __restrict__ out,
                                         float* __restrict__ sm) {
  const int tid = (int)threadIdx.x;
  const int c = tid & 7;   // column
  const int g = tid >> 3;  // row group (16 rows each), 0..63
  const long base = 512 + ((long)blockIdx.x - 1) * kTileC;

  // Stage region rows [base-16, base+1040) col-major: 1056*8 = 2112 float4.
#pragma unroll
  for (int k = 0; k < 5; ++k) {
    const int idx = tid + k * kThreads;
    if (idx < (kRegC * 8) / 4) {
      const int r = idx >> 1;        // region row
      const int cp = (idx & 1) * 4;  // column 0 or 4
      const float4 v = *(const float4*)&y[(base - kHaloC + r) * 8 + cp];
      sm[(cp + 0) * kColS + r] = v.x;
      sm[(cp + 1) * kColS + r] = v.y;
      sm[(cp + 2) * kColS + r] = v.z;
      sm[(cp + 3) * kColS + r] = v.w;
    }
  }
  __syncthreads();

  // Thread outputs: region rows 16+r0 .. 16+r0+15 (r0 = 16g).
  // Inputs: region rows r0+8 .. r0+39 (32 rows, 16B-aligned b128 reads).
  float acc[16];
#pragma unroll
  for (int k = 0; k < 16; ++k) acc[k] = 0.0f;
  const int r0 = g * 16;
  const float* col = &sm[c * kColS + r0 + 8];
#pragma unroll
  for (int q = 0; q < 8; ++q) {
    const float4 x = *(const float4*)&col[4 * q];
    const float xv[4] = {x.x, x.y, x.z, x.w};
#pragma unroll
    for (int i = 0; i < 4; ++i) {
      const int m = 4 * q + i;  // input = region row r0+8+m
#pragma unroll
      for (int k2 = 0; k2 < 16; ++k2) {
        // tap t = (r0+8+m) - (16+r0+k2) = m-8-k2; w index = m-k2 in [0,16].
        if (m - k2 >= 0 && m - k2 <= 2 * kR) {
          acc[k2] = fmaf(kWT.w[m - k2], xv[i], acc[k2]);
        }
      }
    }
  }

  // Epilogue: transpose through LDS -> fully coalesced float4 stores.
  __syncthreads();  // all fragment reads done before overwrite
#pragma unroll
  for (int k = 0; k < 16; ++k) {
    sm[c * kColS + r0 + k] = acc[k];  // output row r0+k of column c
  }
  __syncthreads();
#pragma unroll
  for (int k = 0; k < 4; ++k) {
    const int idx = tid + k * kThreads;  // 1024*8/4 = 2048 float4
    const int r = idx >> 1;
    const int cp = (idx & 1) * 4;
    float4 v;
    v.x = sm[(cp + 0) * kColS + r];
    v.y = sm[(cp + 1) * kColS + r];
    v.z = sm[(cp + 2) * kColS + r];
    v.w = sm[(cp + 3) * kColS + r];
    *(float4*)&out[(base + r) * 8 + cp] = v;
  }
}

// ------------- Edge blocks: literal 32 sweeps (R7-R9 path) -------------
__device__ __forceinline__ void run_edge(const float* __restrict__ y,
                                         float* __restrict__ out,
                                         float* __restrict__ st,
                                         long base_out) {
  const int tid = (int)threadIdx.x;
  const int w = tid >> 6;  // wave id == column
  const int l = tid & 63;  // lane == row segment (rows kS*l .. kS*l+9)
  const long base = base_out - kHaloE;  // region row 0 (may be <0 or >N-640)

  // Stage y row-major (pad-9), guarded.
#pragma unroll
  for (int k = 0; k < 5; ++k) {
    const int idx = (tid + k * kThreads) * 2;  // 5120 floats = 640*8
    const int r = idx >> 3, c = idx & 7;
    const long gi = base + r;
    float2 v = make_float2(0.0f, 0.0f);
    if (gi >= 0 && gi < kN) v = *(const float2*)&y[gi * 8 + c];
    st[r * kPad + c] = v.x;
    st[r * kPad + c + 1] = v.y;
  }
  __syncthreads();

  float buf[kS];
  float ky[kS];
#pragma unroll
  for (int r = 0; r < kS; ++r) {
    const float v = st[(l * kS + r) * kPad + w];
    buf[r] = v;
    ky[r] = kC2 * v;
  }

  for (int s = 0; s < kSweeps; ++s) {
    const float om2_0 = __shfl_up(buf[kS - 2], 1, 64);
    const float om1_0 = __shfl_up(buf[kS - 1], 1, 64);
    const float hp1 = __shfl_down(buf[0], 1, 64);
    const float hp2 = __shfl_down(buf[1], 1, 64);
    float om2 = om2_0, om1 = om1_0;
#pragma unroll
    for (int r = 0; r < kS; ++r) {
      const float o0 = buf[r];
      const float d1 = (r < kS - 1) ? buf[r + 1] : hp1;
      const float d2 = (r < kS - 2) ? buf[r + 2] : ((r == kS - 2) ? hp1 : hp2);
      const long gi = base + l * kS + r;
      const int lr = l * kS + r;
      float lap = om2 - 4.0f * om1 + 6.0f * o0 - 4.0f * d1 + d2;
      if (gi == 1) lap = -2.0f * om1 + 5.0f * o0 - 4.0f * d1 + d2;
      const float t = fmaf(-kC2, o0, o0) + ky[r];
      float nv = fmaf(-kC1, lap, t);
      const bool frozen =
          (gi <= 0) || (gi >= kN - 2) || (lr < 2) || (lr >= kRegE - 2);
      if (frozen) nv = o0;
      buf[r] = nv;
      om2 = om1;
      om1 = o0;
    }
  }

  __syncthreads();
#pragma unroll
  for (int r = 0; r < kS; ++r) {
    st[(l * kS + r) * kPad + w] = buf[r];
  }
  __syncthreads();
#pragma unroll
  for (int k = 0; k < 4; ++k) {
    const int idx = (tid + k * kThreads) * 2;  // 4096 valid floats
    const int r = idx >> 3, c = idx & 7;
    float2 v;
    v.x = st[(kHaloE + r) * kPad + c];
    v.y = st[(kHaloE + r) * kPad + c + 1];
    *(float2*)&out[(base + kHaloE + r) * 8 + c] = v;
  }
}

__global__ __launch_bounds__(kThreads) void biharm_kernel(
    const float* __restrict__ y, float* __restrict__ out) {
  __shared__ __align__(16) float sm[kSmemFloats];  // 34,176 B
  // Branch is block-uniform -> __syncthreads inside is safe.
  if (blockIdx.x == 0) {
    run_edge(y, out, sm, 0);
  } else if (blockIdx.x == (int)gridDim.x - 1) {
    run_edge(y, out, sm, (long)kN - kTileE);
  } else {
    run_conv(y, out, sm);
  }
}

extern "C" void kernel_launch(void* const* d_in, const int* in_sizes, int n_in,
                              void* d_out, int out_size, void* d_ws,
                              size_t ws_size, hipStream_t stream) {
  const float* yp = (const float*)d_in[0];
  float* outp = (float*)d_out;
  // 1023 conv tiles of 1024 rows covering [512, N-512) + 2 edge blocks.
  biharm_kernel<<<dim3(1025), dim3(kThreads), 0, stream>>>(yp, outp);
}